// Round 23
// baseline (193.633 us; speedup 1.0000x reference)
//
#include <hip/hip_runtime.h>
#include <cstddef>

// Problem constants (match reference)
#define Bb   4
#define CI   128
#define CO   128
#define Hh   128
#define Ww   128
#define HW   (Hh*Ww)
#define NOFF 18      // 2*K*K
#define NTAP 9       // K*K
#define KTOT (NTAP*CI)   // 1152
#define NSTEP 36     // K-steps of 32: NTAP*4

// Pipeline geometry: 4 chunks, af16 double-buffered (same 75.5MB footprint)
#define CHUNK 16384
#define NSAMP ((CHUNK/16)*9)   // 9216 sample blocks per chunk
#define NGEMM (CHUNK/32)       // 512 gemm blocks per chunk
#define NOFFH ((Bb*HW/16)/2)   // 2048 offsets blocks per half (2 chunks)

typedef short short8 __attribute__((ext_vector_type(8)));
typedef _Float16 half8 __attribute__((ext_vector_type(8)));
typedef float floatx4 __attribute__((ext_vector_type(4)));

__device__ inline unsigned short bf16_rne_bits(float f) {
    unsigned u = __float_as_uint(f);
    unsigned r = u + 0x7FFFu + ((u >> 16) & 1u);
    return (unsigned short)(r >> 16);
}
__device__ inline float bf16_bits_to_f32(unsigned short h) {
    return __uint_as_float((unsigned)h << 16);
}
__device__ inline unsigned short f32_to_f16_bits(float f) {
    union { _Float16 h; unsigned short u; } cv;
    cv.h = (_Float16)f;            // RNE
    return cv.u;
}

// ---------------------------------------------------------------------------
// K0: transpose x NCHW -> NHWC; emits fp16 + bf16 hi/lo planes.
// ---------------------------------------------------------------------------
__global__ __launch_bounds__(256) void k_transpose(const float* __restrict__ x,
                                                   _Float16* __restrict__ xt16,
                                                   unsigned short* __restrict__ xbh,
                                                   unsigned short* __restrict__ xbl) {
    __shared__ float tile[32][33];
    int b  = blockIdx.z;
    int c0 = blockIdx.y * 32;
    int p0 = blockIdx.x * 32;
    int tx = threadIdx.x;
    int ty = threadIdx.y;
    const float* xb = x + (size_t)b * CI * HW;
    size_t obase = (size_t)b * HW * CI;
#pragma unroll
    for (int i = 0; i < 4; ++i) {
        int c = c0 + ty + 8 * i;
        tile[ty + 8 * i][tx] = xb[(size_t)c * HW + p0 + tx];
    }
    __syncthreads();
#pragma unroll
    for (int i = 0; i < 4; ++i) {
        int p = p0 + ty + 8 * i;
        float v = tile[tx][ty + 8 * i];
        size_t o = obase + (size_t)p * CI + c0 + tx;
        xt16[o] = (_Float16)v;
        unsigned short hb = bf16_rne_bits(v);
        xbh[o] = hb;
        xbl[o] = bf16_rne_bits(v - bf16_bits_to_f32(hb));
    }
}

// ---------------------------------------------------------------------------
// K0b: weight transforms (unchanged).
// ---------------------------------------------------------------------------
__global__ __launch_bounds__(256) void k_weights(const float* __restrict__ w_off,
                                                 const float* __restrict__ w_main,
                                                 unsigned short* __restrict__ wofh,
                                                 unsigned short* __restrict__ wofl,
                                                 unsigned short* __restrict__ wf16) {
    int idx = blockIdx.x * 256 + threadIdx.x;
    int stride = gridDim.x * 256;
    for (int i = idx; i < 9 * 4 * 2 * 512; i += stride) {
        int j  = i & 7;
        int l  = (i >> 3) & 63;
        int nt = (i >> 9) & 1;
        int ks = (i >> 10) & 3;
        int t  = i >> 12;
        int oc = nt * 16 + (l & 15);
        int c  = ks * 32 + (l >> 4) * 8 + j;
        float f = (oc < NOFF) ? w_off[(oc * CI + c) * 9 + t] : 0.f;
        unsigned short hb = bf16_rne_bits(f);
        wofh[i] = hb;
        wofl[i] = bf16_rne_bits(f - bf16_bits_to_f32(hb));
    }
    for (int i = idx; i < CO * KTOT; i += stride) {
        int j  = i & 7;
        int l  = (i >> 3) & 63;
        int g  = (i >> 9) & 7;
        int ks = (i >> 12) & 3;
        int t  = i >> 14;
        int o  = g * 16 + (l & 15);
        int c  = ks * 32 + (l >> 4) * 8 + j;
        wf16[i] = f32_to_f16_bits(w_main[(o * CI + c) * 9 + t]);
    }
}

// ---------------------------------------------------------------------------
// dev_offsets: R21/R22 k_offsets body, parameterized by linear block id.
// blk covers px [blk*16, blk*16+16) (px-major: b*1024 + h*8 + wt).
// ---------------------------------------------------------------------------
__device__ __forceinline__ void dev_offsets(int blk,
                                            const unsigned short* __restrict__ xbh,
                                            const unsigned short* __restrict__ xbl,
                                            const unsigned short* __restrict__ wofh,
                                            const unsigned short* __restrict__ wofl,
                                            const float* __restrict__ b_off,
                                            float2* __restrict__ coords) {
    __shared__ __align__(16) unsigned short ph[3 * 18 * 128];  // 13,824 B
    __shared__ __align__(16) unsigned short pl[3 * 18 * 128];  // 13,824 B
    __shared__ float rawp[2][16][19];                          //  2,432 B
    int wt  = blk & 7;
    int h   = (blk >> 3) & 127;
    int b   = blk >> 10;
    int w0  = wt * 16;
    int tid  = threadIdx.x;
    int lane = tid & 63;
    int wave = tid >> 6;

    size_t xb0 = (size_t)b * HW * CI;
    for (int i = tid; i < 3 * 18 * 64; i += 256) {
        int c2  = i & 63;
        int col = (i >> 6) % 18;
        int r   = i / (18 * 64);
        int gy  = h - 1 + r;
        int gx  = w0 - 1 + col;
        unsigned vh = 0, vl = 0;
        if (gy >= 0 && gy < Hh && gx >= 0 && gx < Ww) {
            size_t o = xb0 + ((size_t)gy * Ww + gx) * CI + c2 * 2;
            vh = *(const unsigned*)(xbh + o);
            vl = *(const unsigned*)(xbl + o);
        }
        int byte = (((r * 18 + col) * 128) + c2 * 2) * 2;
        byte ^= (col & 7) << 4;
        *(unsigned*)((char*)ph + byte) = vh;
        *(unsigned*)((char*)pl + byte) = vl;
    }
    __syncthreads();

    int nt  = wave & 1;
    int th  = wave >> 1;
    int l15 = lane & 15, lhi = lane >> 4;
    floatx4 accE = (floatx4){0.f, 0.f, 0.f, 0.f};
    floatx4 accO = (floatx4){0.f, 0.f, 0.f, 0.f};
    const short8* bhp = (const short8*)wofh;
    const short8* blp = (const short8*)wofl;

#define TAP_STEP(t)                                                              \
    {                                                                            \
        const int ki = (t) / 3, kj = (t) % 3;                                    \
        int colb = l15 + kj;                                                     \
        int rowoff = (ki * 18 + colb) * 256;                                     \
        _Pragma("unroll")                                                        \
        for (int ks = 0; ks < 4; ++ks) {                                         \
            int abyte = (rowoff + ks * 64 + lhi * 16) ^ ((colb & 7) << 4);       \
            short8 Ah = *(const short8*)((char*)ph + abyte);                     \
            short8 Al = *(const short8*)((char*)pl + abyte);                     \
            size_t bi = (size_t)(((t) * 4 + ks) * 2 + nt) * 64 + lane;           \
            short8 Bh = bhp[bi];                                                 \
            short8 Bl = blp[bi];                                                 \
            floatx4& a = (ks & 1) ? accO : accE;                                 \
            a = __builtin_amdgcn_mfma_f32_16x16x32_bf16(Ah, Bh, a, 0, 0, 0);     \
            a = __builtin_amdgcn_mfma_f32_16x16x32_bf16(Ah, Bl, a, 0, 0, 0);     \
            a = __builtin_amdgcn_mfma_f32_16x16x32_bf16(Al, Bh, a, 0, 0, 0);     \
        }                                                                        \
    }
    if (th == 0) {
        TAP_STEP(0) TAP_STEP(1) TAP_STEP(2) TAP_STEP(3)
    } else {
        TAP_STEP(4) TAP_STEP(5) TAP_STEP(6) TAP_STEP(7) TAP_STEP(8)
    }
#undef TAP_STEP

    int oc = nt * 16 + l15;
    if (oc < NOFF) {
        float bo = (th == 0) ? b_off[oc] : 0.f;
#pragma unroll
        for (int r = 0; r < 4; ++r) {
            int px = lhi * 4 + r;
            rawp[th][px][oc] = (accE[r] + accO[r]) + bo;
        }
    }
    __syncthreads();

    for (int i = tid; i < 16 * NTAP; i += 256) {
        int px = i / NTAP;
        int t  = i % NTAP;
        int ki = t / 3, kj = t % 3;
        float offx = 0.f, offy = 0.f;
        for (int q = 0; q <= ki; ++q) {
            int idx = q * 6 + kj * 2 + 0;
            offx += rawp[0][px][idx] + rawp[1][px][idx];
        }
        for (int q = 0; q <= kj; ++q) {
            int idx = ki * 6 + q * 2 + 1;
            offy += rawp[0][px][idx] + rawp[1][px][idx];
        }
        int wg = w0 + px;
        float xg = -1.0f + 2.0f * (float)wg / 127.0f;
        float yg = -1.0f + 2.0f * (float)h  / 127.0f;
        float gxn = xg + offx;
        float gyn = yg + offy;
        float ix = ((gxn + 1.0f) * (float)Ww - 1.0f) * 0.5f;
        float iy = ((gyn + 1.0f) * (float)Hh - 1.0f) * 0.5f;
        coords[(((size_t)b * Hh + h) * Ww + wg) * NTAP + t] = make_float2(ix, iy);
    }
}

// ---------------------------------------------------------------------------
// dev_sample: R22 body (wave = 16px x 1 tap x 1 ks, 4-corner MLP gather).
// ---------------------------------------------------------------------------
__device__ __forceinline__ void dev_sample(int bid, int nb,
                                           const _Float16* __restrict__ xt16,
                                           const float2* __restrict__ coords,
                                           unsigned short* __restrict__ af16,
                                           int q0) {
    int cpx = nb >> 3;
    int blkid = (bid & 7) * cpx + (bid >> 3);   // XCD remap (nb%8==0)
    int task = blkid * 4 + (threadIdx.x >> 6);  // = Pl*36 + tap*4 + ks
    int lane = threadIdx.x & 63;
    int Pl   = task / 36;
    int rem  = task - Pl * 36;
    int tap  = rem >> 2;
    int ks   = rem & 3;
    int r = lane & 15, q = lane >> 4;
    int p = q0 + Pl * 16 + r;
    int b = p >> 14;

    float2 co = coords[(size_t)p * NTAP + tap];
    float ix = co.x, iy = co.y;
    float fx0 = floorf(ix), fy0 = floorf(iy);
    int x0 = (int)fx0, y0 = (int)fy0;
    int x1 = x0 + 1,   y1 = y0 + 1;
    float wx1 = ix - fx0, wy1 = iy - fy0;
    float wx0 = 1.f - wx1, wy0 = 1.f - wy1;
    bool vx0 = (x0 >= 0) & (x0 < Ww);
    bool vx1 = (x1 >= 0) & (x1 < Ww);
    bool vy0 = (y0 >= 0) & (y0 < Hh);
    bool vy1 = (y1 >= 0) & (y1 < Hh);
    int cx0 = min(max(x0, 0), Ww - 1), cx1 = min(max(x1, 0), Ww - 1);
    int cy0 = min(max(y0, 0), Hh - 1), cy1 = min(max(y1, 0), Hh - 1);
    float w00 = (vy0 && vx0) ? wy0 * wx0 : 0.f;
    float w01 = (vy0 && vx1) ? wy0 * wx1 : 0.f;
    float w10 = (vy1 && vx0) ? wy1 * wx0 : 0.f;
    float w11 = (vy1 && vx1) ? wy1 * wx1 : 0.f;

    const _Float16* xb = xt16 + (size_t)b * HW * CI + ks * 32 + q * 8;
    half8 a8 = *(const half8*)(xb + ((size_t)cy0 * Ww + cx0) * CI);
    half8 b8 = *(const half8*)(xb + ((size_t)cy0 * Ww + cx1) * CI);
    half8 c8 = *(const half8*)(xb + ((size_t)cy1 * Ww + cx0) * CI);
    half8 d8 = *(const half8*)(xb + ((size_t)cy1 * Ww + cx1) * CI);
    short8 hv;
#pragma unroll
    for (int j = 0; j < 8; ++j) {
        float v = w00 * (float)a8[j] + w01 * (float)b8[j]
                + w10 * (float)c8[j] + w11 * (float)d8[j];
        hv[j] = (short)f32_to_f16_bits(v);
    }
    *(short8*)(af16 + ((size_t)task * 64 + lane) * 8) = hv;
}

// ---------------------------------------------------------------------------
// dev_gemm: R22 body (fp16 register GEMM, ping-pong prefetch).
// ---------------------------------------------------------------------------
__device__ __forceinline__ void dev_gemm(int bid, int nb,
                                         const unsigned short* __restrict__ af16,
                                         const unsigned short* __restrict__ wf16,
                                         const float* __restrict__ b_main,
                                         float* __restrict__ out, int q0) {
    __shared__ __align__(16) float epi[CO * 33];   // 16,896 B (epilogue only)
    int cpx = nb >> 3;
    int blk = (bid & 7) * cpx + (bid >> 3);        // XCD remap (nb%8==0)
    int tid = threadIdx.x, lane = tid & 63, wave = tid >> 6;
    int wave_n = wave & 1, wave_m = wave >> 1;
    int l15 = lane & 15, lhi = lane >> 4;
    int P = blk * 2 + wave_m;

    const half8* ah = (const half8*)af16 + (size_t)P * NSTEP * 64 + lane;
    const half8* bh = (const half8*)wf16 + (size_t)wave_n * 4 * 64 + lane;

    floatx4 acc[4];
#pragma unroll
    for (int n = 0; n < 4; ++n) acc[n] = (floatx4){0.f, 0.f, 0.f, 0.f};

    half8 A0, B0[4], A1, B1[4];
    A0 = ah[0];
#pragma unroll
    for (int n = 0; n < 4; ++n) B0[n] = bh[(size_t)n * 64];

#pragma unroll 2
    for (int s = 0; s < NSTEP; s += 2) {
        A1 = ah[(size_t)(s + 1) * 64];
#pragma unroll
        for (int n = 0; n < 4; ++n) B1[n] = bh[(size_t)((s + 1) * 8 + n) * 64];
#pragma unroll
        for (int n = 0; n < 4; ++n)
            acc[n] = __builtin_amdgcn_mfma_f32_16x16x32_f16(A0, B0[n], acc[n], 0, 0, 0);
        if (s + 2 < NSTEP) {
            A0 = ah[(size_t)(s + 2) * 64];
#pragma unroll
            for (int n = 0; n < 4; ++n) B0[n] = bh[(size_t)((s + 2) * 8 + n) * 64];
        }
#pragma unroll
        for (int n = 0; n < 4; ++n)
            acc[n] = __builtin_amdgcn_mfma_f32_16x16x32_f16(A1, B1[n], acc[n], 0, 0, 0);
    }

#pragma unroll
    for (int n = 0; n < 4; ++n) {
        int o = wave_n * 64 + n * 16 + l15;
#pragma unroll
        for (int rr = 0; rr < 4; ++rr) {
            int px = wave_m * 16 + lhi * 4 + rr;
            epi[o * 33 + px] = acc[n][rr];
        }
    }
    __syncthreads();
    int p_blk = q0 + blk * 32;
    int b = p_blk >> 14, hw = p_blk & 16383;
    float* ob = out + (size_t)b * CO * HW + hw;
    for (int i = tid; i < CO * 32; i += 256) {
        int o  = i >> 5;
        int px = i & 31;
        __builtin_nontemporal_store(epi[o * 33 + px] + b_main[o],
                                    &ob[(size_t)o * HW + px]);
    }
}

// ---------------------------------------------------------------------------
// Kernel wrappers: pure + role-split pair launches (pipeline co-scheduling).
// ---------------------------------------------------------------------------
__global__ __launch_bounds__(256, 2) void k_offsets_part(
        const unsigned short* xbh, const unsigned short* xbl,
        const unsigned short* wofh, const unsigned short* wofl,
        const float* b_off, float2* coords, int blk0) {
    dev_offsets(blockIdx.x + blk0, xbh, xbl, wofh, wofl, b_off, coords);
}

// sample(chunk) first [long role], then offsets(half1)
__global__ __launch_bounds__(256, 2) void k_pair_os(
        const _Float16* xt16, const float2* coords, unsigned short* af_s, int q0s,
        const unsigned short* xbh, const unsigned short* xbl,
        const unsigned short* wofh, const unsigned short* wofl,
        const float* b_off, float2* coords_w, int off_blk0) {
    if ((int)blockIdx.x < NSAMP)
        dev_sample(blockIdx.x, NSAMP, xt16, coords, af_s, q0s);
    else
        dev_offsets((int)blockIdx.x - NSAMP + off_blk0, xbh, xbl, wofh, wofl,
                    b_off, coords_w);
}

// gemm(prev chunk) first [fat blocks start immediately], then sample(chunk)
__global__ __launch_bounds__(256, 4) void k_pair_sg(
        const unsigned short* af_g, int q0g,
        unsigned short* af_s, int q0s,
        const _Float16* xt16, const float2* coords,
        const unsigned short* wf16, const float* b_main, float* out) {
    if ((int)blockIdx.x < NGEMM)
        dev_gemm(blockIdx.x, NGEMM, af_g, wf16, b_main, out, q0g);
    else
        dev_sample((int)blockIdx.x - NGEMM, NSAMP, xt16, coords, af_s, q0s);
}

__global__ __launch_bounds__(256, 4) void k_gemm_p(
        const unsigned short* af_g, const unsigned short* wf16,
        const float* b_main, float* out, int q0) {
    dev_gemm(blockIdx.x, NGEMM, af_g, wf16, b_main, out, q0);
}

// ---------------------------------------------------------------------------
extern "C" void kernel_launch(void* const* d_in, const int* in_sizes, int n_in,
                              void* d_out, int out_size, void* d_ws, size_t ws_size,
                              hipStream_t stream) {
    const float* x      = (const float*)d_in[0];
    const float* w_off  = (const float*)d_in[1];
    const float* b_off  = (const float*)d_in[2];
    const float* w_main = (const float*)d_in[3];
    const float* b_main = (const float*)d_in[4];
    float* out = (float*)d_out;

    // workspace layout (bytes):
    //  xt16 16,777,216 | xbh 16,777,216 | xbl 16,777,216 | coords 4,718,592
    //  | wofrag 2x73,728 | wf16 294,912 | af16 dbuf 2 x 37,748,736
    char* base = (char*)d_ws;
    _Float16*       xt16 = (_Float16*)base;
    unsigned short* xbh  = (unsigned short*)(base + 16777216);
    unsigned short* xbl  = (unsigned short*)(base + 2 * 16777216);
    float2*         coords = (float2*)(base + 3 * 16777216);
    unsigned short* wofh = (unsigned short*)(base + 3 * 16777216 + 4718592);
    unsigned short* wofl = wofh + 9 * 4 * 2 * 512;
    unsigned short* wf16 = wofl + 9 * 4 * 2 * 512;
    size_t fixed_b = 3ull * 16777216 + 4718592
                   + 2 * (9 * 4 * 2 * 512) * 2 + (size_t)CO * KTOT * 2;
    unsigned short* afA = (unsigned short*)(base + fixed_b);
    unsigned short* afB = afA + (size_t)CHUNK * KTOT;

    k_transpose<<<dim3(HW / 32, CI / 32, Bb), dim3(32, 8), 0, stream>>>(x, xt16, xbh, xbl);
    k_weights<<<576, 256, 0, stream>>>(w_off, w_main, wofh, wofl, wf16);

    // Pipeline: o(h0) | s(c0)||o(h1) | g(c0)||s(c1) | g(c1)||s(c2)
    //           | g(c2)||s(c3) | g(c3)
    k_offsets_part<<<NOFFH, 256, 0, stream>>>(xbh, xbl, wofh, wofl, b_off, coords, 0);
    k_pair_os<<<NSAMP + NOFFH, 256, 0, stream>>>(xt16, coords, afA, 0,
                                                 xbh, xbl, wofh, wofl, b_off,
                                                 coords, NOFFH);
    k_pair_sg<<<NGEMM + NSAMP, 256, 0, stream>>>(afA, 0,        afB, CHUNK,
                                                 xt16, coords, wf16, b_main, out);
    k_pair_sg<<<NGEMM + NSAMP, 256, 0, stream>>>(afB, CHUNK,    afA, 2 * CHUNK,
                                                 xt16, coords, wf16, b_main, out);
    k_pair_sg<<<NGEMM + NSAMP, 256, 0, stream>>>(afA, 2 * CHUNK, afB, 3 * CHUNK,
                                                 xt16, coords, wf16, b_main, out);
    k_gemm_p<<<NGEMM, 256, 0, stream>>>(afB, wf16, b_main, out, 3 * CHUNK);
}

// Round 24
// 189.493 us; speedup vs baseline: 1.0218x; 1.0218x over previous
//
#include <hip/hip_runtime.h>
#include <cstddef>

// Problem constants (match reference)
#define Bb   4
#define CI   128
#define CO   128
#define Hh   128
#define Ww   128
#define HW   (Hh*Ww)
#define NOFF 18      // 2*K*K
#define NTAP 9       // K*K
#define KTOT (NTAP*CI)   // 1152
#define NSTEP 36     // K-steps of 32: NTAP*4

typedef short short8 __attribute__((ext_vector_type(8)));
typedef _Float16 half8 __attribute__((ext_vector_type(8)));
typedef float floatx4 __attribute__((ext_vector_type(4)));

// bf16 RNE split helpers (no NaN/inf in this data)
__device__ inline unsigned short bf16_rne_bits(float f) {
    unsigned u = __float_as_uint(f);
    unsigned r = u + 0x7FFFu + ((u >> 16) & 1u);
    return (unsigned short)(r >> 16);
}
__device__ inline float bf16_bits_to_f32(unsigned short h) {
    return __uint_as_float((unsigned)h << 16);
}
__device__ inline unsigned short f32_to_f16_bits(float f) {
    union { _Float16 h; unsigned short u; } cv;
    cv.h = (_Float16)f;            // RNE
    return cv.u;
}

// ---------------------------------------------------------------------------
// K0: transpose x NCHW -> NHWC; emits fp16 (k_sample gather) and bf16 hi/lo
// planes (k_offsets' LDS staging source — split done once here).
// ---------------------------------------------------------------------------
__global__ __launch_bounds__(256) void k_transpose(const float* __restrict__ x,
                                                   _Float16* __restrict__ xt16,
                                                   unsigned short* __restrict__ xbh,
                                                   unsigned short* __restrict__ xbl) {
    __shared__ float tile[32][33];
    int b  = blockIdx.z;
    int c0 = blockIdx.y * 32;
    int p0 = blockIdx.x * 32;
    int tx = threadIdx.x;
    int ty = threadIdx.y;
    const float* xb = x + (size_t)b * CI * HW;
    size_t obase = (size_t)b * HW * CI;
#pragma unroll
    for (int i = 0; i < 4; ++i) {
        int c = c0 + ty + 8 * i;
        tile[ty + 8 * i][tx] = xb[(size_t)c * HW + p0 + tx];
    }
    __syncthreads();
#pragma unroll
    for (int i = 0; i < 4; ++i) {
        int p = p0 + ty + 8 * i;
        float v = tile[tx][ty + 8 * i];
        size_t o = obase + (size_t)p * CI + c0 + tx;
        xt16[o] = (_Float16)v;
        unsigned short hb = bf16_rne_bits(v);
        xbh[o] = hb;
        xbl[o] = bf16_rne_bits(v - bf16_bits_to_f32(hb));
    }
}

// ---------------------------------------------------------------------------
// K0b: weight transforms (unchanged).
// ---------------------------------------------------------------------------
__global__ __launch_bounds__(256) void k_weights(const float* __restrict__ w_off,
                                                 const float* __restrict__ w_main,
                                                 unsigned short* __restrict__ wofh,
                                                 unsigned short* __restrict__ wofl,
                                                 unsigned short* __restrict__ wf16) {
    int idx = blockIdx.x * 256 + threadIdx.x;
    int stride = gridDim.x * 256;
    for (int i = idx; i < 9 * 4 * 2 * 512; i += stride) {
        int j  = i & 7;
        int l  = (i >> 3) & 63;
        int nt = (i >> 9) & 1;
        int ks = (i >> 10) & 3;
        int t  = i >> 12;                       // 0..8  (= ky*3+kx)
        int oc = nt * 16 + (l & 15);
        int c  = ks * 32 + (l >> 4) * 8 + j;
        float f = (oc < NOFF) ? w_off[(oc * CI + c) * 9 + t] : 0.f;
        unsigned short hb = bf16_rne_bits(f);
        wofh[i] = hb;
        wofl[i] = bf16_rne_bits(f - bf16_bits_to_f32(hb));
    }
    for (int i = idx; i < CO * KTOT; i += stride) {
        int j  = i & 7;
        int l  = (i >> 3) & 63;
        int g  = (i >> 9) & 7;
        int ks = (i >> 12) & 3;
        int t  = i >> 14;
        int o  = g * 16 + (l & 15);
        int c  = ks * 32 + (l >> 4) * 8 + j;
        wf16[i] = f32_to_f16_bits(w_main[(o * CI + c) * 9 + t]);
    }
}

// ---------------------------------------------------------------------------
// K1: offset conv via split-bf16 MFMA + cumsum + coords.
// 16-px tile: patch 27.6 KB -> 5 blocks/CU. 4 waves = (oc-tile) x (tap-half);
// partials combined via rawp[2][16][19] in the cumsum stage.
// ---------------------------------------------------------------------------
__global__ __launch_bounds__(256, 2) void k_offsets(const unsigned short* __restrict__ xbh,
                                                    const unsigned short* __restrict__ xbl,
                                                    const unsigned short* __restrict__ wofh,
                                                    const unsigned short* __restrict__ wofl,
                                                    const float* __restrict__ b_off,
                                                    float2* __restrict__ coords) {
    __shared__ __align__(16) unsigned short ph[3 * 18 * 128];  // 13,824 B
    __shared__ __align__(16) unsigned short pl[3 * 18 * 128];  // 13,824 B
    __shared__ float rawp[2][16][19];                          //  2,432 B
    int blk = blockIdx.x;
    int wt  = blk & 7;
    int h   = (blk >> 3) & 127;
    int b   = blk >> 10;
    int w0  = wt * 16;
    int tid  = threadIdx.x;
    int lane = tid & 63;
    int wave = tid >> 6;

    // ---- stage patch: copy bf16 hi/lo planes (4B per task per plane) ----
    size_t xb0 = (size_t)b * HW * CI;
    for (int i = tid; i < 3 * 18 * 64; i += 256) {
        int c2  = i & 63;
        int col = (i >> 6) % 18;
        int r   = i / (18 * 64);
        int gy  = h - 1 + r;
        int gx  = w0 - 1 + col;
        unsigned vh = 0, vl = 0;
        if (gy >= 0 && gy < Hh && gx >= 0 && gx < Ww) {
            size_t o = xb0 + ((size_t)gy * Ww + gx) * CI + c2 * 2;
            vh = *(const unsigned*)(xbh + o);
            vl = *(const unsigned*)(xbl + o);
        }
        int byte = (((r * 18 + col) * 128) + c2 * 2) * 2;
        byte ^= (col & 7) << 4;
        *(unsigned*)((char*)ph + byte) = vh;
        *(unsigned*)((char*)pl + byte) = vl;
    }
    __syncthreads();

    // ---- MFMA: wave = (nt = oc-tile, th = tap-half) ----
    int nt  = wave & 1;
    int th  = wave >> 1;
    int l15 = lane & 15, lhi = lane >> 4;
    floatx4 accE = (floatx4){0.f, 0.f, 0.f, 0.f};
    floatx4 accO = (floatx4){0.f, 0.f, 0.f, 0.f};
    const short8* bhp = (const short8*)wofh;
    const short8* blp = (const short8*)wofl;

#define TAP_STEP(t)                                                              \
    {                                                                            \
        const int ki = (t) / 3, kj = (t) % 3;                                    \
        int colb = l15 + kj;                                                     \
        int rowoff = (ki * 18 + colb) * 256;                                     \
        _Pragma("unroll")                                                        \
        for (int ks = 0; ks < 4; ++ks) {                                         \
            int abyte = (rowoff + ks * 64 + lhi * 16) ^ ((colb & 7) << 4);       \
            short8 Ah = *(const short8*)((char*)ph + abyte);                     \
            short8 Al = *(const short8*)((char*)pl + abyte);                     \
            size_t bi = (size_t)(((t) * 4 + ks) * 2 + nt) * 64 + lane;           \
            short8 Bh = bhp[bi];                                                 \
            short8 Bl = blp[bi];                                                 \
            floatx4& a = (ks & 1) ? accO : accE;                                 \
            a = __builtin_amdgcn_mfma_f32_16x16x32_bf16(Ah, Bh, a, 0, 0, 0);     \
            a = __builtin_amdgcn_mfma_f32_16x16x32_bf16(Ah, Bl, a, 0, 0, 0);     \
            a = __builtin_amdgcn_mfma_f32_16x16x32_bf16(Al, Bh, a, 0, 0, 0);     \
        }                                                                        \
    }
    if (th == 0) {
        TAP_STEP(0) TAP_STEP(1) TAP_STEP(2) TAP_STEP(3)
    } else {
        TAP_STEP(4) TAP_STEP(5) TAP_STEP(6) TAP_STEP(7) TAP_STEP(8)
    }
#undef TAP_STEP

    int oc = nt * 16 + l15;
    if (oc < NOFF) {
        float bo = (th == 0) ? b_off[oc] : 0.f;   // bias added once
#pragma unroll
        for (int r = 0; r < 4; ++r) {
            int px = lhi * 4 + r;
            rawp[th][px][oc] = (accE[r] + accO[r]) + bo;
        }
    }
    __syncthreads();

    // ---- cumsum + coordinate math (sums the two tap-half partials) ----
    for (int i = tid; i < 16 * NTAP; i += 256) {
        int px = i / NTAP;
        int t  = i % NTAP;
        int ki = t / 3, kj = t % 3;
        float offx = 0.f, offy = 0.f;
        for (int q = 0; q <= ki; ++q) {
            int idx = q * 6 + kj * 2 + 0;
            offx += rawp[0][px][idx] + rawp[1][px][idx];
        }
        for (int q = 0; q <= kj; ++q) {
            int idx = ki * 6 + q * 2 + 1;
            offy += rawp[0][px][idx] + rawp[1][px][idx];
        }
        int wg = w0 + px;
        float xg = -1.0f + 2.0f * (float)wg / 127.0f;
        float yg = -1.0f + 2.0f * (float)h  / 127.0f;
        float gxn = xg + offx;
        float gyn = yg + offy;
        float ix = ((gxn + 1.0f) * (float)Ww - 1.0f) * 0.5f;
        float iy = ((gyn + 1.0f) * (float)Hh - 1.0f) * 0.5f;
        coords[(((size_t)b * Hh + h) * Ww + wg) * NTAP + t] = make_float2(ix, iy);
    }
}

// ---------------------------------------------------------------------------
// K2a: k_sample — bilinear sample from fp16 xt16, fp16 A-fragments out.
// Wave = 16 px x 1 tap; lane=(px, c-octet); 4 ks iterations per wave.
// No LDS, no barriers: pure TLP. (R21 best-measured variant.)
//  afrag idx (half8 units): (Pl*36 + tap*4 + ks)*64 + lane  — 2304 B/px.
// ---------------------------------------------------------------------------
__global__ __launch_bounds__(256) void k_sample(const _Float16* __restrict__ xt16,
                                                const float2* __restrict__ coords,
                                                unsigned short* __restrict__ af16,
                                                int q0) {
    int nb = gridDim.x;
    int blkid = blockIdx.x;
    int cpx = nb >> 3;
    blkid = (blkid & 7) * cpx + (blkid >> 3);   // XCD-contiguous remap (nb%8==0)
    int task = blkid * 4 + (threadIdx.x >> 6);
    int lane = threadIdx.x & 63;
    int Pl   = task / 9;
    int tap  = task - Pl * 9;
    int r = lane & 15, q = lane >> 4;
    int p = q0 + Pl * 16 + r;          // global pixel
    int b = p >> 14;

    float2 co = coords[(size_t)p * NTAP + tap];
    float ix = co.x, iy = co.y;
    float fx0 = floorf(ix), fy0 = floorf(iy);
    int x0 = (int)fx0, y0 = (int)fy0;
    int x1 = x0 + 1,   y1 = y0 + 1;
    float wx1 = ix - fx0, wy1 = iy - fy0;
    float wx0 = 1.f - wx1, wy0 = 1.f - wy1;
    bool vx0 = (x0 >= 0) & (x0 < Ww);
    bool vx1 = (x1 >= 0) & (x1 < Ww);
    bool vy0 = (y0 >= 0) & (y0 < Hh);
    bool vy1 = (y1 >= 0) & (y1 < Hh);
    int cx0 = min(max(x0, 0), Ww - 1), cx1 = min(max(x1, 0), Ww - 1);
    int cy0 = min(max(y0, 0), Hh - 1), cy1 = min(max(y1, 0), Hh - 1);
    float w00 = (vy0 && vx0) ? wy0 * wx0 : 0.f;
    float w01 = (vy0 && vx1) ? wy0 * wx1 : 0.f;
    float w10 = (vy1 && vx0) ? wy1 * wx0 : 0.f;
    float w11 = (vy1 && vx1) ? wy1 * wx1 : 0.f;

    const _Float16* xb  = xt16 + (size_t)b * HW * CI + q * 8;
    const _Float16* r00 = xb + ((size_t)cy0 * Ww + cx0) * CI;
    const _Float16* r01 = xb + ((size_t)cy0 * Ww + cx1) * CI;
    const _Float16* r10 = xb + ((size_t)cy1 * Ww + cx0) * CI;
    const _Float16* r11 = xb + ((size_t)cy1 * Ww + cx1) * CI;
    size_t obase = ((size_t)(Pl * 36 + tap * 4) * 64 + lane) * 8;

#pragma unroll
    for (int ks = 0; ks < 4; ++ks) {
        int c = ks * 32;
        half8 a8 = *(const half8*)(r00 + c);
        half8 b8 = *(const half8*)(r01 + c);
        half8 c8 = *(const half8*)(r10 + c);
        half8 d8 = *(const half8*)(r11 + c);
        short8 hv;
#pragma unroll
        for (int j = 0; j < 8; ++j) {
            float v = w00 * (float)a8[j] + w01 * (float)b8[j]
                    + w10 * (float)c8[j] + w11 * (float)d8[j];
            hv[j] = (short)f32_to_f16_bits(v);
        }
        *(short8*)(af16 + obase + (size_t)ks * 512) = hv;
    }
}

// ---------------------------------------------------------------------------
// K2b: k_gemm — fp16 register GEMM on pre-sampled fragments (unchanged).
// ---------------------------------------------------------------------------
__global__ __launch_bounds__(256, 4) void k_gemm(const unsigned short* __restrict__ af16,
                                                 const unsigned short* __restrict__ wf16,
                                                 const float* __restrict__ b_main,
                                                 float* __restrict__ out, int q0) {
    __shared__ __align__(16) float epi[CO * 33];   // 16,896 B (epilogue only)
    int nb = gridDim.x;
    int cpx = nb >> 3;
    int blk = blockIdx.x;
    blk = (blk & 7) * cpx + (blk >> 3);            // XCD remap (nb%8==0)
    int tid = threadIdx.x, lane = tid & 63, wave = tid >> 6;
    int wave_n = wave & 1, wave_m = wave >> 1;
    int l15 = lane & 15, lhi = lane >> 4;
    int P = blk * 2 + wave_m;                      // local 16-px tile

    const half8* ah = (const half8*)af16 + (size_t)P * NSTEP * 64 + lane;
    const half8* bh = (const half8*)wf16 + (size_t)wave_n * 4 * 64 + lane;

    floatx4 acc[4];
#pragma unroll
    for (int n = 0; n < 4; ++n) acc[n] = (floatx4){0.f, 0.f, 0.f, 0.f};

    half8 A0, B0[4], A1, B1[4];
    A0 = ah[0];
#pragma unroll
    for (int n = 0; n < 4; ++n) B0[n] = bh[(size_t)n * 64];

#pragma unroll 2
    for (int s = 0; s < NSTEP; s += 2) {
        A1 = ah[(size_t)(s + 1) * 64];
#pragma unroll
        for (int n = 0; n < 4; ++n) B1[n] = bh[(size_t)((s + 1) * 8 + n) * 64];
#pragma unroll
        for (int n = 0; n < 4; ++n)
            acc[n] = __builtin_amdgcn_mfma_f32_16x16x32_f16(A0, B0[n], acc[n], 0, 0, 0);
        if (s + 2 < NSTEP) {
            A0 = ah[(size_t)(s + 2) * 64];
#pragma unroll
            for (int n = 0; n < 4; ++n) B0[n] = bh[(size_t)((s + 2) * 8 + n) * 64];
        }
#pragma unroll
        for (int n = 0; n < 4; ++n)
            acc[n] = __builtin_amdgcn_mfma_f32_16x16x32_f16(A1, B1[n], acc[n], 0, 0, 0);
    }

    // ---- epilogue: transpose through LDS for coalesced stores ----
#pragma unroll
    for (int n = 0; n < 4; ++n) {
        int o = wave_n * 64 + n * 16 + l15;
#pragma unroll
        for (int rr = 0; rr < 4; ++rr) {
            int px = wave_m * 16 + lhi * 4 + rr;
            epi[o * 33 + px] = acc[n][rr];
        }
    }
    __syncthreads();
    int p_blk = q0 + blk * 32;              // 32 px contiguous within one h-row
    int b = p_blk >> 14, hw = p_blk & 16383;
    float* ob = out + (size_t)b * CO * HW + hw;
    for (int i = tid; i < CO * 32; i += 256) {
        int o  = i >> 5;
        int px = i & 31;
        __builtin_nontemporal_store(epi[o * 33 + px] + b_main[o],
                                    &ob[(size_t)o * HW + px]);
    }
}

// ---------------------------------------------------------------------------
extern "C" void kernel_launch(void* const* d_in, const int* in_sizes, int n_in,
                              void* d_out, int out_size, void* d_ws, size_t ws_size,
                              hipStream_t stream) {
    const float* x      = (const float*)d_in[0];
    const float* w_off  = (const float*)d_in[1];
    const float* b_off  = (const float*)d_in[2];
    const float* w_main = (const float*)d_in[3];
    const float* b_main = (const float*)d_in[4];
    float* out = (float*)d_out;

    // workspace layout (bytes):
    //  xt16 16,777,216 | xbh 16,777,216 | xbl 16,777,216 | coords 4,718,592
    //  | wofrag 2x73,728 | wf16 294,912 | af16 (chunked, 2304 B/px)
    char* base = (char*)d_ws;
    _Float16*       xt16 = (_Float16*)base;
    unsigned short* xbh  = (unsigned short*)(base + 16777216);
    unsigned short* xbl  = (unsigned short*)(base + 2 * 16777216);
    float2*         coords = (float2*)(base + 3 * 16777216);
    unsigned short* wofh = (unsigned short*)(base + 3 * 16777216 + 4718592);
    unsigned short* wofl = wofh + 9 * 4 * 2 * 512;
    unsigned short* wf16 = wofl + 9 * 4 * 2 * 512;
    size_t fixed_b = 3ull * 16777216 + 4718592
                   + 2 * (9 * 4 * 2 * 512) * 2 + (size_t)CO * KTOT * 2;
    unsigned short* af16 = (unsigned short*)(base + fixed_b);

    // chunk: multiple of 2048 px, capped at 32768 (af16 75.5 MB + planes
    // stays L3-resident; same-buffer reuse across chunks).
    size_t avail = (ws_size > fixed_b) ? (ws_size - fixed_b) : 0;
    long long maxpx = (long long)(avail / 2304);
    int chunk = (int)((maxpx / 2048) * 2048);
    if (chunk > 32768) chunk = 32768;
    if (chunk < 2048) chunk = 2048;          // minimum footprint fallback

    k_transpose<<<dim3(HW / 32, CI / 32, Bb), dim3(32, 8), 0, stream>>>(x, xt16, xbh, xbl);
    k_weights<<<576, 256, 0, stream>>>(w_off, w_main, wofh, wofl, wf16);
    k_offsets<<<Bb * Hh * (Ww / 16), 256, 0, stream>>>(xbh, xbl, wofh, wofl, b_off, coords);
    for (int q0 = 0; q0 < Bb * HW; q0 += chunk) {
        int np = Bb * HW - q0; if (np > chunk) np = chunk;
        k_sample<<<(np / 16) * 9 / 4, 256, 0, stream>>>(xt16, coords, af16, q0);
        k_gemm<<<np / 32, 256, 0, stream>>>(af16, wf16, b_main, out, q0);
    }
}